// Round 4
// baseline (640.529 us; speedup 1.0000x reference)
//
#include <hip/hip_runtime.h>

#define E_EDGES 320000
#define N_NODES 10000

typedef __attribute__((ext_vector_type(8))) short short8;
typedef __attribute__((ext_vector_type(4))) float floatx4;
typedef __attribute__((ext_vector_type(4))) short short4v;

__device__ __forceinline__ unsigned short f2bf(float f) {
    union { float f; unsigned int i; } v; v.f = f;
    unsigned int u = v.i;
    return (unsigned short)((u + 0x7fffu + ((u >> 16) & 1u)) >> 16);
}

// ---- MFMA layer: acc[mt][nt] = In[64 x K] @ W[K x N] for this wave's n-stripe.
// A from LDS (row-major bf16, stride istride), B from global Wt[n][k] (bf16, k contiguous).
// Verified gfx950 layouts: A: m=lane&15, k=quad*8+j ; B: n=lane&15, k=quad*8+j ;
// C/D: col=lane&15, row=quad*4+reg.
template<int K, int NT>
__device__ __forceinline__ void layer_acc(const unsigned short* __restrict__ in, int istride,
                                          const unsigned short* __restrict__ wt,
                                          int lane, int n0, floatx4 (&acc)[4][NT])
{
    const int quad = lane >> 4;
    const int mrow = lane & 15;
    floatx4 zero = {0.f, 0.f, 0.f, 0.f};
#pragma unroll
    for (int mt = 0; mt < 4; ++mt)
#pragma unroll
        for (int nt = 0; nt < NT; ++nt)
            acc[mt][nt] = zero;

    for (int kt = 0; kt < K / 32; ++kt) {
        const int koff = kt * 32 + quad * 8;
        short8 a[4];
        short8 b[NT];
#pragma unroll
        for (int mt = 0; mt < 4; ++mt)
            a[mt] = *(const short8*)&in[(mt * 16 + mrow) * istride + koff];
#pragma unroll
        for (int nt = 0; nt < NT; ++nt)
            b[nt] = *(const short8*)&wt[(size_t)(n0 + nt * 16 + mrow) * K + koff];
#pragma unroll
        for (int nt = 0; nt < NT; ++nt)
#pragma unroll
            for (int mt = 0; mt < 4; ++mt)
                acc[mt][nt] = __builtin_amdgcn_mfma_f32_16x16x32_bf16(a[mt], b[nt], acc[mt][nt], 0, 0, 0);
    }
}

template<int NT>
__device__ __forceinline__ void store_lds(floatx4 (&acc)[4][NT], const float* __restrict__ bias,
                                          int lane, int n0, unsigned short* __restrict__ out, int ostride,
                                          bool relu)
{
    const int quad = lane >> 4, mrow = lane & 15;
#pragma unroll
    for (int nt = 0; nt < NT; ++nt) {
        int col = n0 + nt * 16 + mrow;
        float bv = bias[col];
#pragma unroll
        for (int mt = 0; mt < 4; ++mt) {
#pragma unroll
            for (int r = 0; r < 4; ++r) {
                float v = acc[mt][nt][r] + bv;
                if (relu) v = v > 0.f ? v : 0.f;
                out[(mt * 16 + quad * 4 + r) * ostride + col] = f2bf(v);
            }
        }
    }
}

// ---------------- weight transpose + fp32->bf16 cast prep ----------------
struct TDesc { const float* src; unsigned short* dst; int nElem; int logN; int K; int blockStart; };
struct TArgs { TDesc d[8]; };

__global__ void transpose_kernel(TArgs a)
{
    int b = blockIdx.x;
    int i = 0;
#pragma unroll
    for (int j = 1; j < 8; ++j)
        if (b >= a.d[j].blockStart) i = j;
    const TDesc t = a.d[i];
    int idx = (b - t.blockStart) * 256 + threadIdx.x;
    if (idx < t.nElem) {
        int n = idx & ((1 << t.logN) - 1);
        int k = idx >> t.logN;
        t.dst[(size_t)n * t.K + k] = f2bf(t.src[idx]);
    }
}

// ---------------- edge MLP + atomic scatter ----------------
__global__ __launch_bounds__(256, 2) void edge_kernel(
    const float* __restrict__ x,
    const int* __restrict__ eidx,   // int32: [2][E]
    const float* __restrict__ ea,
    const unsigned short* __restrict__ wt0, const float* __restrict__ b0,
    const unsigned short* __restrict__ wt1, const float* __restrict__ b1,
    const unsigned short* __restrict__ wt2, const float* __restrict__ b2,
    const unsigned short* __restrict__ wt3, const float* __restrict__ b3,
    float* __restrict__ s, int* __restrict__ cnt)
{
    __shared__ __align__(16) unsigned short Hbig[64 * 264];   // [64][256+8] bf16
    __shared__ __align__(16) unsigned short HsA[64 * 136];    // [64][128+8]
    __shared__ __align__(16) unsigned short HsB[64 * 136];
    __shared__ int rs[64];
    __shared__ int cs[64];

    const int tid = threadIdx.x;
    const int e0 = blockIdx.x * 64;

    if (tid < 64) {
        int r = eidx[e0 + tid];
        int c = eidx[E_EDGES + e0 + tid];
        rs[tid] = r;
        cs[tid] = c;
        atomicAdd(&cnt[c], 1);
    }
    __syncthreads();

    // Build H0 = [x[row] | edge_attr] : 64 rows x 256 cols, fp32 load -> bf16 LDS.
#pragma unroll
    for (int i = 0; i < 16; ++i) {
        int task = tid + i * 256;
        int edge = task >> 6, part = task & 63;
        float4 v;
        if (part < 32) v = *(const float4*)(x + (size_t)rs[edge] * 128 + part * 4);
        else           v = *(const float4*)(ea + (size_t)(e0 + edge) * 128 + (part - 32) * 4);
        short4v o;
        o[0] = (short)f2bf(v.x); o[1] = (short)f2bf(v.y);
        o[2] = (short)f2bf(v.z); o[3] = (short)f2bf(v.w);
        *(short4v*)&Hbig[edge * 264 + part * 4] = o;
    }
    __syncthreads();

    const int lane = tid & 63;
    const int wave = tid >> 6;

    {
        floatx4 acc[4][2];
        layer_acc<256, 2>(Hbig, 264, wt0, lane, wave * 32, acc);
        store_lds<2>(acc, b0, lane, wave * 32, HsA, 136, true);
    }
    __syncthreads();
    {
        floatx4 acc[4][2];
        layer_acc<128, 2>(HsA, 136, wt1, lane, wave * 32, acc);
        store_lds<2>(acc, b1, lane, wave * 32, HsB, 136, true);
    }
    __syncthreads();
    {
        floatx4 acc[4][2];
        layer_acc<128, 2>(HsB, 136, wt2, lane, wave * 32, acc);
        store_lds<2>(acc, b2, lane, wave * 32, HsA, 136, true);
    }
    __syncthreads();
    {
        floatx4 acc[4][4];
        layer_acc<128, 4>(HsA, 136, wt3, lane, wave * 64, acc);
        const int quad = lane >> 4, mrow = lane & 15;
#pragma unroll
        for (int nt = 0; nt < 4; ++nt) {
            int colg = wave * 64 + nt * 16 + mrow;
            float bv = b3[colg];
#pragma unroll
            for (int mt = 0; mt < 4; ++mt) {
#pragma unroll
                for (int r = 0; r < 4; ++r) {
                    int row = mt * 16 + quad * 4 + r;
                    float v = acc[mt][nt][r] + bv;
                    v = v > 0.f ? v : 0.f;
                    atomicAdd(&s[(size_t)cs[row] * 256 + colg], v);
                }
            }
        }
    }
}

// ---------------- node MLP ----------------
__global__ __launch_bounds__(256, 1) void node_kernel(
    const float* __restrict__ x,
    const float* __restrict__ g,
    const float* __restrict__ s,
    const int* __restrict__ cnt,
    const unsigned short* __restrict__ wt0, const float* __restrict__ b0,
    const unsigned short* __restrict__ wt1, const float* __restrict__ b1,
    const unsigned short* __restrict__ wt2, const float* __restrict__ b2,
    const unsigned short* __restrict__ wt3, const float* __restrict__ b3,
    float* __restrict__ out)
{
    __shared__ __align__(16) unsigned short Abig[64 * 424];   // [64][416+8] bf16
    __shared__ __align__(16) unsigned short HsA[64 * 136];
    __shared__ __align__(16) unsigned short HsB[64 * 136];

    const int tid = threadIdx.x;
    const int node0 = blockIdx.x * 64;

    // x part: cols 0..127 (fp32 -> bf16)
#pragma unroll
    for (int i = 0; i < 8; ++i) {
        int task = tid + i * 256;
        int row = task >> 5, part = task & 31;
        int node = node0 + row;
        short4v o = {0, 0, 0, 0};
        if (node < N_NODES) {
            float4 v = *(const float4*)(x + (size_t)node * 128 + part * 4);
            o[0] = (short)f2bf(v.x); o[1] = (short)f2bf(v.y);
            o[2] = (short)f2bf(v.z); o[3] = (short)f2bf(v.w);
        }
        *(short4v*)&Abig[row * 424 + part * 4] = o;
    }
    // agg part: cols 128..383 (s / max(cnt,1), fp32 -> bf16)
#pragma unroll
    for (int i = 0; i < 16; ++i) {
        int task = tid + i * 256;
        int row = task >> 6, part = task & 63;
        int node = node0 + row;
        short4v o = {0, 0, 0, 0};
        if (node < N_NODES) {
            float c = (float)cnt[node];
            float inv = 1.f / (c > 1.f ? c : 1.f);
            floatx4 v = *(const floatx4*)(s + (size_t)node * 256 + part * 4);
            o[0] = (short)f2bf(v[0] * inv);
            o[1] = (short)f2bf(v[1] * inv);
            o[2] = (short)f2bf(v[2] * inv);
            o[3] = (short)f2bf(v[3] * inv);
        }
        *(short4v*)&Abig[row * 424 + 128 + part * 4] = o;
    }
    // global part: cols 384..415
#pragma unroll
    for (int i = 0; i < 2; ++i) {
        int task = tid + i * 256;
        int row = task >> 3, part = task & 7;
        float4 v = *(const float4*)(g + part * 4);
        short4v o;
        o[0] = (short)f2bf(v.x); o[1] = (short)f2bf(v.y);
        o[2] = (short)f2bf(v.z); o[3] = (short)f2bf(v.w);
        *(short4v*)&Abig[row * 424 + 384 + part * 4] = o;
    }
    __syncthreads();

    const int lane = tid & 63;
    const int wave = tid >> 6;

    {
        floatx4 acc[4][2];
        layer_acc<416, 2>(Abig, 424, wt0, lane, wave * 32, acc);
        store_lds<2>(acc, b0, lane, wave * 32, HsA, 136, true);
    }
    __syncthreads();
    {
        floatx4 acc[4][2];
        layer_acc<128, 2>(HsA, 136, wt1, lane, wave * 32, acc);
        store_lds<2>(acc, b1, lane, wave * 32, HsB, 136, true);
    }
    __syncthreads();
    {
        floatx4 acc[4][2];
        layer_acc<128, 2>(HsB, 136, wt2, lane, wave * 32, acc);
        store_lds<2>(acc, b2, lane, wave * 32, HsA, 136, true);
    }
    __syncthreads();
    {
        floatx4 acc[4][2];
        layer_acc<128, 2>(HsA, 136, wt3, lane, wave * 32, acc);
        const int quad = lane >> 4, mrow = lane & 15;
#pragma unroll
        for (int nt = 0; nt < 2; ++nt) {
            int col = wave * 32 + nt * 16 + mrow;
            float bv = b3[col];
#pragma unroll
            for (int mt = 0; mt < 4; ++mt) {
#pragma unroll
                for (int r = 0; r < 4; ++r) {
                    int row = mt * 16 + quad * 4 + r;
                    int node = node0 + row;
                    if (node < N_NODES)
                        out[(size_t)node * 128 + col] = acc[mt][nt][r] + bv;  // fp32 output
                }
            }
        }
    }
}

extern "C" void kernel_launch(void* const* d_in, const int* in_sizes, int n_in,
                              void* d_out, int out_size, void* d_ws, size_t ws_size,
                              hipStream_t stream)
{
    (void)in_sizes; (void)n_in; (void)out_size; (void)ws_size;

    const float* x  = (const float*)d_in[0];
    const int* eidx = (const int*)d_in[1];
    const float* ea = (const float*)d_in[2];
    const float* g  = (const float*)d_in[3];

    const float* w1[4]  = { (const float*)d_in[4],  (const float*)d_in[6],
                            (const float*)d_in[8],  (const float*)d_in[10] };
    const float* bb1[4] = { (const float*)d_in[5],  (const float*)d_in[7],
                            (const float*)d_in[9],  (const float*)d_in[11] };
    const float* w2[4]  = { (const float*)d_in[12], (const float*)d_in[14],
                            (const float*)d_in[16], (const float*)d_in[18] };
    const float* bb2[4] = { (const float*)d_in[13], (const float*)d_in[15],
                            (const float*)d_in[17], (const float*)d_in[19] };

    char* p = (char*)d_ws;
    unsigned short* wt1_0 = (unsigned short*)p; p += 256 * 128 * 2;
    unsigned short* wt1_1 = (unsigned short*)p; p += 128 * 128 * 2;
    unsigned short* wt1_2 = (unsigned short*)p; p += 128 * 128 * 2;
    unsigned short* wt1_3 = (unsigned short*)p; p += 128 * 256 * 2;
    unsigned short* wt2_0 = (unsigned short*)p; p += 416 * 128 * 2;
    unsigned short* wt2_1 = (unsigned short*)p; p += 128 * 128 * 2;
    unsigned short* wt2_2 = (unsigned short*)p; p += 128 * 128 * 2;
    unsigned short* wt2_3 = (unsigned short*)p; p += 128 * 128 * 2;
    float* s = (float*)p;  p += (size_t)N_NODES * 256 * 4;
    int* cnt = (int*)p;    p += (size_t)N_NODES * 4;

    // zero accumulators (s then cnt, contiguous)
    hipMemsetAsync(s, 0, (size_t)N_NODES * 256 * 4 + (size_t)N_NODES * 4, stream);

    TArgs ta;
    int bs = 0;
    auto set = [&](int i, const float* src, unsigned short* dst, int K, int Nn, int logN) {
        ta.d[i].src = src; ta.d[i].dst = dst; ta.d[i].nElem = K * Nn;
        ta.d[i].logN = logN; ta.d[i].K = K; ta.d[i].blockStart = bs;
        bs += (K * Nn + 255) / 256;
    };
    set(0, w1[0], wt1_0, 256, 128, 7);
    set(1, w1[1], wt1_1, 128, 128, 7);
    set(2, w1[2], wt1_2, 128, 128, 7);
    set(3, w1[3], wt1_3, 128, 256, 8);
    set(4, w2[0], wt2_0, 416, 128, 7);
    set(5, w2[1], wt2_1, 128, 128, 7);
    set(6, w2[2], wt2_2, 128, 128, 7);
    set(7, w2[3], wt2_3, 128, 128, 7);

    hipLaunchKernelGGL(transpose_kernel, dim3(bs), dim3(256), 0, stream, ta);

    hipLaunchKernelGGL(edge_kernel, dim3(E_EDGES / 64), dim3(256), 0, stream,
                       x, eidx, ea,
                       wt1_0, bb1[0], wt1_1, bb1[1], wt1_2, bb1[2], wt1_3, bb1[3],
                       s, cnt);

    hipLaunchKernelGGL(node_kernel, dim3((N_NODES + 63) / 64), dim3(256), 0, stream,
                       x, g, s, cnt,
                       wt2_0, bb2[0], wt2_1, bb2[1], wt2_2, bb2[2], wt2_3, bb2[3],
                       (float*)d_out);
}

// Round 5
// 591.049 us; speedup vs baseline: 1.0837x; 1.0837x over previous
//
#include <hip/hip_runtime.h>

#define E_EDGES 320000
#define N_NODES 10000

typedef __attribute__((ext_vector_type(8))) short short8;
typedef __attribute__((ext_vector_type(4))) float floatx4;
typedef __attribute__((ext_vector_type(4))) short short4v;

__device__ __forceinline__ unsigned short f2bf(float f) {
    union { float f; unsigned int i; } v; v.f = f;
    unsigned int u = v.i;
    return (unsigned short)((u + 0x7fffu + ((u >> 16) & 1u)) >> 16);
}

// ---- MFMA layer: acc[mt][nt] = In[64 x K] @ W[K x N] for this wave's n-stripe.
// A from LDS (row-major bf16, stride istride), B from global Wt[n][k] (bf16, k contiguous).
// Verified gfx950 layouts: A: m=lane&15, k=quad*8+j ; B: n=lane&15, k=quad*8+j ;
// C/D: col=lane&15, row=quad*4+reg.
template<int K, int NT>
__device__ __forceinline__ void layer_acc(const unsigned short* __restrict__ in, int istride,
                                          const unsigned short* __restrict__ wt,
                                          int lane, int n0, floatx4 (&acc)[4][NT])
{
    const int quad = lane >> 4;
    const int mrow = lane & 15;
    floatx4 zero = {0.f, 0.f, 0.f, 0.f};
#pragma unroll
    for (int mt = 0; mt < 4; ++mt)
#pragma unroll
        for (int nt = 0; nt < NT; ++nt)
            acc[mt][nt] = zero;

    for (int kt = 0; kt < K / 32; ++kt) {
        const int koff = kt * 32 + quad * 8;
        short8 a[4];
        short8 b[NT];
#pragma unroll
        for (int mt = 0; mt < 4; ++mt)
            a[mt] = *(const short8*)&in[(mt * 16 + mrow) * istride + koff];
#pragma unroll
        for (int nt = 0; nt < NT; ++nt)
            b[nt] = *(const short8*)&wt[(size_t)(n0 + nt * 16 + mrow) * K + koff];
#pragma unroll
        for (int nt = 0; nt < NT; ++nt)
#pragma unroll
            for (int mt = 0; mt < 4; ++mt)
                acc[mt][nt] = __builtin_amdgcn_mfma_f32_16x16x32_bf16(a[mt], b[nt], acc[mt][nt], 0, 0, 0);
    }
}

template<int NT>
__device__ __forceinline__ void store_lds(floatx4 (&acc)[4][NT], const float* __restrict__ bias,
                                          int lane, int n0, unsigned short* __restrict__ out, int ostride,
                                          bool relu)
{
    const int quad = lane >> 4, mrow = lane & 15;
#pragma unroll
    for (int nt = 0; nt < NT; ++nt) {
        int col = n0 + nt * 16 + mrow;
        float bv = bias[col];
#pragma unroll
        for (int mt = 0; mt < 4; ++mt) {
#pragma unroll
            for (int r = 0; r < 4; ++r) {
                float v = acc[mt][nt][r] + bv;
                if (relu) v = v > 0.f ? v : 0.f;
                out[(mt * 16 + quad * 4 + r) * ostride + col] = f2bf(v);
            }
        }
    }
}

// ---------------- weight transpose + fp32->bf16 cast prep ----------------
struct TDesc { const float* src; unsigned short* dst; int nElem; int logN; int K; int blockStart; };
struct TArgs { TDesc d[8]; };

__global__ void transpose_kernel(TArgs a)
{
    int b = blockIdx.x;
    int i = 0;
#pragma unroll
    for (int j = 1; j < 8; ++j)
        if (b >= a.d[j].blockStart) i = j;
    const TDesc t = a.d[i];
    int idx = (b - t.blockStart) * 256 + threadIdx.x;
    if (idx < t.nElem) {
        int n = idx & ((1 << t.logN) - 1);
        int k = idx >> t.logN;
        t.dst[(size_t)n * t.K + k] = f2bf(t.src[idx]);
    }
}

// ---------------- CSR prep: histogram, scan, bucket fill ----------------
__global__ void hist_kernel(const int* __restrict__ eidx, int* __restrict__ cnt)
{
    int e = blockIdx.x * 256 + threadIdx.x;
    atomicAdd(&cnt[eidx[E_EDGES + e]], 1);
}

__global__ void scan_kernel(const int* __restrict__ cnt, int* __restrict__ fill)
{
    // exclusive prefix sum over cnt[0..N) -> fill[] (bucket write pointers)
    __shared__ int partial[256];
    const int CH = 40;                      // 256*40 = 10240 >= N_NODES
    int tid = threadIdx.x;
    int base = tid * CH;
    int local[CH];
    int sum = 0;
#pragma unroll
    for (int j = 0; j < CH; ++j) {
        int idx = base + j;
        int c = (idx < N_NODES) ? cnt[idx] : 0;
        local[j] = c;
        sum += c;
    }
    partial[tid] = sum;
    __syncthreads();
    for (int o = 1; o < 256; o <<= 1) {
        int v = (tid >= o) ? partial[tid - o] : 0;
        __syncthreads();
        partial[tid] += v;
        __syncthreads();
    }
    int run = partial[tid] - sum;           // exclusive prefix of this chunk
#pragma unroll
    for (int j = 0; j < CH; ++j) {
        int idx = base + j;
        if (idx < N_NODES) fill[idx] = run;
        run += local[j];
    }
}

__global__ void fill_kernel(const int* __restrict__ eidx, int* __restrict__ fill,
                            int* __restrict__ elist, int* __restrict__ rowp, int* __restrict__ dstp)
{
    int e = blockIdx.x * 256 + threadIdx.x;
    int c = eidx[E_EDGES + e];
    int r = eidx[e];
    int pos = atomicAdd(&fill[c], 1);
    elist[pos] = e;
    rowp[pos] = r;
    dstp[pos] = c;
}

// ---------------- edge MLP over destination-sorted edges + run-reduced scatter ----------------
__global__ __launch_bounds__(256, 2) void edge_kernel(
    const float* __restrict__ x,
    const float* __restrict__ ea,
    const int* __restrict__ elist, const int* __restrict__ rowp, const int* __restrict__ dstp,
    const unsigned short* __restrict__ wt0, const float* __restrict__ b0,
    const unsigned short* __restrict__ wt1, const float* __restrict__ b1,
    const unsigned short* __restrict__ wt2, const float* __restrict__ b2,
    const unsigned short* __restrict__ wt3, const float* __restrict__ b3,
    float* __restrict__ s)
{
    // Unioned LDS: H0 [64][264] bf16 @0 (33792 B); H1 [64][136] bf16 @33792;
    // H2 [64][136] bf16 @51200; H3 aliases H1; G [64][260] fp32 @0 (66560 B).
    // Barrier discipline: G write only after all waves finished reading H3.
    __shared__ __align__(16) char U[68608];
    __shared__ int es[64];
    __shared__ int rs[64];
    __shared__ int ds[64];

    unsigned short* H0 = (unsigned short*)U;
    unsigned short* H1 = (unsigned short*)(U + 33792);
    unsigned short* H2 = (unsigned short*)(U + 51200);
    unsigned short* H3 = H1;
    float* G = (float*)U;

    const int tid = threadIdx.x;
    const int p0 = blockIdx.x * 64;

    if (tid < 64) {
        es[tid] = elist[p0 + tid];
        rs[tid] = rowp[p0 + tid];
        ds[tid] = dstp[p0 + tid];
    }
    __syncthreads();

    // Stage H0 = [x[src] | edge_attr[e]] : 64 rows x 256 cols, fp32 -> bf16
#pragma unroll
    for (int i = 0; i < 16; ++i) {
        int task = tid + i * 256;
        int row = task >> 6, part = task & 63;
        float4 v;
        if (part < 32) v = *(const float4*)(x + (size_t)rs[row] * 128 + part * 4);
        else           v = *(const float4*)(ea + (size_t)es[row] * 128 + (part - 32) * 4);
        short4v o;
        o[0] = (short)f2bf(v.x); o[1] = (short)f2bf(v.y);
        o[2] = (short)f2bf(v.z); o[3] = (short)f2bf(v.w);
        *(short4v*)&H0[row * 264 + part * 4] = o;
    }
    __syncthreads();

    const int lane = tid & 63;
    const int wave = tid >> 6;

    {
        floatx4 acc[4][2];
        layer_acc<256, 2>(H0, 264, wt0, lane, wave * 32, acc);
        store_lds<2>(acc, b0, lane, wave * 32, H1, 136, true);
    }
    __syncthreads();
    {
        floatx4 acc[4][2];
        layer_acc<128, 2>(H1, 136, wt1, lane, wave * 32, acc);
        store_lds<2>(acc, b1, lane, wave * 32, H2, 136, true);
    }
    __syncthreads();
    {
        floatx4 acc[4][2];
        layer_acc<128, 2>(H2, 136, wt2, lane, wave * 32, acc);
        store_lds<2>(acc, b2, lane, wave * 32, H3, 136, true);
    }
    __syncthreads();
    {
        floatx4 acc[4][4];
        layer_acc<128, 4>(H3, 136, wt3, lane, wave * 64, acc);
        __syncthreads();   // all waves done reading H3 before G overwrites it
        const int quad = lane >> 4, mrow = lane & 15;
#pragma unroll
        for (int nt = 0; nt < 4; ++nt) {
            int colg = wave * 64 + nt * 16 + mrow;
            float bv = b3[colg];
#pragma unroll
            for (int mt = 0; mt < 4; ++mt) {
#pragma unroll
                for (int r = 0; r < 4; ++r) {
                    int row = mt * 16 + quad * 4 + r;
                    float v = acc[mt][nt][r] + bv;
                    v = v > 0.f ? v : 0.f;
                    G[row * 260 + colg] = v;   // fp32, no bf16 rounding
                }
            }
        }
    }
    __syncthreads();

    // Run-reduction: dests are sorted, so sum consecutive rows with equal ds and
    // emit one fp32 atomic per (run, col). Branch is wave-uniform (ds same across lanes).
    {
        int col = tid;            // 256 threads = 256 cols
        float sum = 0.f;
#pragma unroll 4
        for (int i = 0; i < 64; ++i) {
            sum += G[i * 260 + col];
            if (i == 63 || ds[i + 1] != ds[i]) {
                atomicAdd(&s[(size_t)ds[i] * 256 + col], sum);
                sum = 0.f;
            }
        }
    }
}

// ---------------- node MLP ----------------
__global__ __launch_bounds__(256, 1) void node_kernel(
    const float* __restrict__ x,
    const float* __restrict__ g,
    const float* __restrict__ s,
    const int* __restrict__ cnt,
    const unsigned short* __restrict__ wt0, const float* __restrict__ b0,
    const unsigned short* __restrict__ wt1, const float* __restrict__ b1,
    const unsigned short* __restrict__ wt2, const float* __restrict__ b2,
    const unsigned short* __restrict__ wt3, const float* __restrict__ b3,
    float* __restrict__ out)
{
    __shared__ __align__(16) unsigned short Abig[64 * 424];   // [64][416+8] bf16
    __shared__ __align__(16) unsigned short HsA[64 * 136];
    __shared__ __align__(16) unsigned short HsB[64 * 136];

    const int tid = threadIdx.x;
    const int node0 = blockIdx.x * 64;

    // x part: cols 0..127 (fp32 -> bf16)
#pragma unroll
    for (int i = 0; i < 8; ++i) {
        int task = tid + i * 256;
        int row = task >> 5, part = task & 31;
        int node = node0 + row;
        short4v o = {0, 0, 0, 0};
        if (node < N_NODES) {
            float4 v = *(const float4*)(x + (size_t)node * 128 + part * 4);
            o[0] = (short)f2bf(v.x); o[1] = (short)f2bf(v.y);
            o[2] = (short)f2bf(v.z); o[3] = (short)f2bf(v.w);
        }
        *(short4v*)&Abig[row * 424 + part * 4] = o;
    }
    // agg part: cols 128..383 (s / max(cnt,1), fp32 -> bf16)
#pragma unroll
    for (int i = 0; i < 16; ++i) {
        int task = tid + i * 256;
        int row = task >> 6, part = task & 63;
        int node = node0 + row;
        short4v o = {0, 0, 0, 0};
        if (node < N_NODES) {
            float c = (float)cnt[node];
            float inv = 1.f / (c > 1.f ? c : 1.f);
            floatx4 v = *(const floatx4*)(s + (size_t)node * 256 + part * 4);
            o[0] = (short)f2bf(v[0] * inv);
            o[1] = (short)f2bf(v[1] * inv);
            o[2] = (short)f2bf(v[2] * inv);
            o[3] = (short)f2bf(v[3] * inv);
        }
        *(short4v*)&Abig[row * 424 + 128 + part * 4] = o;
    }
    // global part: cols 384..415
#pragma unroll
    for (int i = 0; i < 2; ++i) {
        int task = tid + i * 256;
        int row = task >> 3, part = task & 7;
        float4 v = *(const float4*)(g + part * 4);
        short4v o;
        o[0] = (short)f2bf(v.x); o[1] = (short)f2bf(v.y);
        o[2] = (short)f2bf(v.z); o[3] = (short)f2bf(v.w);
        *(short4v*)&Abig[row * 424 + 384 + part * 4] = o;
    }
    __syncthreads();

    const int lane = tid & 63;
    const int wave = tid >> 6;

    {
        floatx4 acc[4][2];
        layer_acc<416, 2>(Abig, 424, wt0, lane, wave * 32, acc);
        store_lds<2>(acc, b0, lane, wave * 32, HsA, 136, true);
    }
    __syncthreads();
    {
        floatx4 acc[4][2];
        layer_acc<128, 2>(HsA, 136, wt1, lane, wave * 32, acc);
        store_lds<2>(acc, b1, lane, wave * 32, HsB, 136, true);
    }
    __syncthreads();
    {
        floatx4 acc[4][2];
        layer_acc<128, 2>(HsB, 136, wt2, lane, wave * 32, acc);
        store_lds<2>(acc, b2, lane, wave * 32, HsA, 136, true);
    }
    __syncthreads();
    {
        floatx4 acc[4][2];
        layer_acc<128, 2>(HsA, 136, wt3, lane, wave * 32, acc);
        const int quad = lane >> 4, mrow = lane & 15;
#pragma unroll
        for (int nt = 0; nt < 2; ++nt) {
            int col = wave * 32 + nt * 16 + mrow;
            float bv = b3[col];
#pragma unroll
            for (int mt = 0; mt < 4; ++mt) {
#pragma unroll
                for (int r = 0; r < 4; ++r) {
                    int row = mt * 16 + quad * 4 + r;
                    int node = node0 + row;
                    if (node < N_NODES)
                        out[(size_t)node * 128 + col] = acc[mt][nt][r] + bv;  // fp32 output
                }
            }
        }
    }
}

extern "C" void kernel_launch(void* const* d_in, const int* in_sizes, int n_in,
                              void* d_out, int out_size, void* d_ws, size_t ws_size,
                              hipStream_t stream)
{
    (void)in_sizes; (void)n_in; (void)out_size; (void)ws_size;

    const float* x  = (const float*)d_in[0];
    const int* eidx = (const int*)d_in[1];
    const float* ea = (const float*)d_in[2];
    const float* g  = (const float*)d_in[3];

    const float* w1[4]  = { (const float*)d_in[4],  (const float*)d_in[6],
                            (const float*)d_in[8],  (const float*)d_in[10] };
    const float* bb1[4] = { (const float*)d_in[5],  (const float*)d_in[7],
                            (const float*)d_in[9],  (const float*)d_in[11] };
    const float* w2[4]  = { (const float*)d_in[12], (const float*)d_in[14],
                            (const float*)d_in[16], (const float*)d_in[18] };
    const float* bb2[4] = { (const float*)d_in[13], (const float*)d_in[15],
                            (const float*)d_in[17], (const float*)d_in[19] };

    char* p = (char*)d_ws;
    unsigned short* wt1_0 = (unsigned short*)p; p += 256 * 128 * 2;
    unsigned short* wt1_1 = (unsigned short*)p; p += 128 * 128 * 2;
    unsigned short* wt1_2 = (unsigned short*)p; p += 128 * 128 * 2;
    unsigned short* wt1_3 = (unsigned short*)p; p += 128 * 256 * 2;
    unsigned short* wt2_0 = (unsigned short*)p; p += 416 * 128 * 2;
    unsigned short* wt2_1 = (unsigned short*)p; p += 128 * 128 * 2;
    unsigned short* wt2_2 = (unsigned short*)p; p += 128 * 128 * 2;
    unsigned short* wt2_3 = (unsigned short*)p; p += 128 * 128 * 2;
    float* s   = (float*)p; p += (size_t)N_NODES * 256 * 4;
    int* cnt   = (int*)p;   p += (size_t)N_NODES * 4;
    int* fill  = (int*)p;   p += (size_t)N_NODES * 4;
    int* elist = (int*)p;   p += (size_t)E_EDGES * 4;
    int* rowp  = (int*)p;   p += (size_t)E_EDGES * 4;
    int* dstp  = (int*)p;   p += (size_t)E_EDGES * 4;

    // zero s + cnt (contiguous); fill/elist/rowp/dstp fully overwritten each launch
    hipMemsetAsync(s, 0, (size_t)N_NODES * 256 * 4 + (size_t)N_NODES * 4, stream);

    TArgs ta;
    int bs = 0;
    auto set = [&](int i, const float* src, unsigned short* dst, int K, int Nn, int logN) {
        ta.d[i].src = src; ta.d[i].dst = dst; ta.d[i].nElem = K * Nn;
        ta.d[i].logN = logN; ta.d[i].K = K; ta.d[i].blockStart = bs;
        bs += (K * Nn + 255) / 256;
    };
    set(0, w1[0], wt1_0, 256, 128, 7);
    set(1, w1[1], wt1_1, 128, 128, 7);
    set(2, w1[2], wt1_2, 128, 128, 7);
    set(3, w1[3], wt1_3, 128, 256, 8);
    set(4, w2[0], wt2_0, 416, 128, 7);
    set(5, w2[1], wt2_1, 128, 128, 7);
    set(6, w2[2], wt2_2, 128, 128, 7);
    set(7, w2[3], wt2_3, 128, 128, 7);

    hipLaunchKernelGGL(transpose_kernel, dim3(bs), dim3(256), 0, stream, ta);
    hipLaunchKernelGGL(hist_kernel, dim3(E_EDGES / 256), dim3(256), 0, stream, eidx, cnt);
    hipLaunchKernelGGL(scan_kernel, dim3(1), dim3(256), 0, stream, cnt, fill);
    hipLaunchKernelGGL(fill_kernel, dim3(E_EDGES / 256), dim3(256), 0, stream,
                       eidx, fill, elist, rowp, dstp);

    hipLaunchKernelGGL(edge_kernel, dim3(E_EDGES / 64), dim3(256), 0, stream,
                       x, ea, elist, rowp, dstp,
                       wt1_0, bb1[0], wt1_1, bb1[1], wt1_2, bb1[2], wt1_3, bb1[3],
                       s);

    hipLaunchKernelGGL(node_kernel, dim3((N_NODES + 63) / 64), dim3(256), 0, stream,
                       x, g, s, cnt,
                       wt2_0, bb2[0], wt2_1, bb2[1], wt2_2, bb2[2], wt2_3, bb2[3],
                       (float*)d_out);
}

// Round 6
// 494.739 us; speedup vs baseline: 1.2947x; 1.1947x over previous
//
#include <hip/hip_runtime.h>

#define E_EDGES 320000
#define N_NODES 10000

typedef __attribute__((ext_vector_type(8))) short short8;
typedef __attribute__((ext_vector_type(4))) float floatx4;
typedef __attribute__((ext_vector_type(4))) short short4v;

__device__ __forceinline__ float bf2f(unsigned short u) {
    union { unsigned int i; float f; } v; v.i = ((unsigned int)u) << 16; return v.f;
}
__device__ __forceinline__ unsigned short f2bf(float f) {
    union { float f; unsigned int i; } v; v.f = f;
    unsigned int u = v.i;
    return (unsigned short)((u + 0x7fffu + ((u >> 16) & 1u)) >> 16);
}

// ---- MFMA layer: acc[mt][nt] = In[64 x K] @ W[K x N] for this wave's n-stripe.
// A from LDS (row-major bf16, stride istride). B from global in FRAGMENT-TILE order:
// [K/32][N/16][64 lanes][8 elems] -> each lane loads 16 B at tileBase + lane*16 (coalesced).
// Verified gfx950 layouts: A: m=lane&15, k=quad*8+j ; B: n=lane&15, k=quad*8+j ;
// C/D: col=lane&15, row=quad*4+reg.
template<int K, int Nn, int NT>
__device__ __forceinline__ void layer_acc(const unsigned short* __restrict__ in, int istride,
                                          const unsigned short* __restrict__ wt,
                                          int lane, int n0, floatx4 (&acc)[4][NT])
{
    const int quad = lane >> 4;
    const int mrow = lane & 15;
    floatx4 zero = {0.f, 0.f, 0.f, 0.f};
#pragma unroll
    for (int mt = 0; mt < 4; ++mt)
#pragma unroll
        for (int nt = 0; nt < NT; ++nt)
            acc[mt][nt] = zero;

#pragma unroll
    for (int kt = 0; kt < K / 32; ++kt) {
        const int koff = kt * 32 + quad * 8;
        short8 a[4];
        short8 b[NT];
#pragma unroll
        for (int mt = 0; mt < 4; ++mt)
            a[mt] = *(const short8*)&in[(mt * 16 + mrow) * istride + koff];
#pragma unroll
        for (int nt = 0; nt < NT; ++nt)
            b[nt] = *(const short8*)&wt[(size_t)(kt * (Nn >> 4) + (n0 >> 4) + nt) * 512 + lane * 8];
#pragma unroll
        for (int nt = 0; nt < NT; ++nt)
#pragma unroll
            for (int mt = 0; mt < 4; ++mt)
                acc[mt][nt] = __builtin_amdgcn_mfma_f32_16x16x32_bf16(a[mt], b[nt], acc[mt][nt], 0, 0, 0);
    }
}

template<int NT>
__device__ __forceinline__ void store_lds(floatx4 (&acc)[4][NT], const float* __restrict__ bias,
                                          int lane, int n0, unsigned short* __restrict__ out, int ostride,
                                          bool relu)
{
    const int quad = lane >> 4, mrow = lane & 15;
#pragma unroll
    for (int nt = 0; nt < NT; ++nt) {
        int col = n0 + nt * 16 + mrow;
        float bv = bias[col];
#pragma unroll
        for (int mt = 0; mt < 4; ++mt) {
#pragma unroll
            for (int r = 0; r < 4; ++r) {
                float v = acc[mt][nt][r] + bv;
                if (relu) v = v > 0.f ? v : 0.f;
                out[(mt * 16 + quad * 4 + r) * ostride + col] = f2bf(v);
            }
        }
    }
}

// ---------------- weight repack: [K][N] fp32 row-major -> bf16 fragment-tile order ----------------
// dst elem index: ((k>>5)*(N>>4) + (n>>4))*512 + ((k>>3)&3)*128 + (n&15)*8 + (k&7)
struct TDesc { const float* src; unsigned short* dst; int nElem; int logN; int blockStart; };
struct TArgs { TDesc d[8]; };

__global__ void transpose_kernel(TArgs a)
{
    int b = blockIdx.x;
    int i = 0;
#pragma unroll
    for (int j = 1; j < 8; ++j)
        if (b >= a.d[j].blockStart) i = j;
    const TDesc t = a.d[i];
    int idx = (b - t.blockStart) * 256 + threadIdx.x;
    if (idx < t.nElem) {
        int n = idx & ((1 << t.logN) - 1);
        int k = idx >> t.logN;
        int ntiles = 1 << (t.logN - 4);
        size_t dsti = ((size_t)(k >> 5) * ntiles + (n >> 4)) * 512
                    + ((k >> 3) & 3) * 128 + (n & 15) * 8 + (k & 7);
        t.dst[dsti] = f2bf(t.src[idx]);
    }
}

// ---------------- CSR prep: histogram, scan, bucket fill ----------------
__global__ void hist_kernel(const int* __restrict__ eidx, int* __restrict__ cnt)
{
    int e = blockIdx.x * 256 + threadIdx.x;
    atomicAdd(&cnt[eidx[E_EDGES + e]], 1);
}

__global__ void scan_kernel(const int* __restrict__ cnt, int* __restrict__ fill)
{
    __shared__ int partial[256];
    const int CH = 40;                      // 256*40 = 10240 >= N_NODES
    int tid = threadIdx.x;
    int base = tid * CH;
    int local[CH];
    int sum = 0;
#pragma unroll
    for (int j = 0; j < CH; ++j) {
        int idx = base + j;
        int c = (idx < N_NODES) ? cnt[idx] : 0;
        local[j] = c;
        sum += c;
    }
    partial[tid] = sum;
    __syncthreads();
    for (int o = 1; o < 256; o <<= 1) {
        int v = (tid >= o) ? partial[tid - o] : 0;
        __syncthreads();
        partial[tid] += v;
        __syncthreads();
    }
    int run = partial[tid] - sum;
#pragma unroll
    for (int j = 0; j < CH; ++j) {
        int idx = base + j;
        if (idx < N_NODES) fill[idx] = run;
        run += local[j];
    }
}

__global__ void fill_kernel(const int* __restrict__ eidx, int* __restrict__ fill,
                            int* __restrict__ elist, int* __restrict__ rowp, int* __restrict__ dstp)
{
    int e = blockIdx.x * 256 + threadIdx.x;
    int c = eidx[E_EDGES + e];
    int r = eidx[e];
    int pos = atomicAdd(&fill[c], 1);
    elist[pos] = e;
    rowp[pos] = r;
    dstp[pos] = c;
}

// ---------------- edge MLP over destination-sorted edges + run-reduced scatter ----------------
__global__ __launch_bounds__(256, 3) void edge_kernel(
    const float* __restrict__ x,
    const float* __restrict__ ea,
    const int* __restrict__ elist, const int* __restrict__ rowp, const int* __restrict__ dstp,
    const unsigned short* __restrict__ wt0, const float* __restrict__ b0,
    const unsigned short* __restrict__ wt1, const float* __restrict__ b1,
    const unsigned short* __restrict__ wt2, const float* __restrict__ b2,
    const unsigned short* __restrict__ wt3, const float* __restrict__ b3,
    float* __restrict__ s)
{
    // Aliased LDS (51200 B total -> 3 blocks/CU):
    //   H0 [64][264] bf16 @0      (33792 B)  - layer0 input
    //   H1 [64][136] bf16 @33792  (17408 B)  - layer0 out / layer1 in
    //   H2 = @0   (aliases dead H0)          - layer1 out / layer2 in
    //   H3 = @33792 (aliases dead H1)        - layer2 out / layer3 in
    //   G  [64][264] bf16 @0 (aliases dead H2; barrier after layer3 A-reads)
    __shared__ __align__(16) char U[51200];
    __shared__ int es[64];
    __shared__ int rs[64];
    __shared__ int ds[64];

    unsigned short* H0 = (unsigned short*)U;
    unsigned short* H1 = (unsigned short*)(U + 33792);
    unsigned short* H2 = (unsigned short*)U;
    unsigned short* H3 = H1;
    unsigned short* G  = (unsigned short*)U;

    const int tid = threadIdx.x;
    const int p0 = blockIdx.x * 64;

    if (tid < 64) {
        es[tid] = elist[p0 + tid];
        rs[tid] = rowp[p0 + tid];
        ds[tid] = dstp[p0 + tid];
    }
    __syncthreads();

    // Stage H0 = [x[src] | edge_attr[e]] : 64 rows x 256 cols, fp32 -> bf16
#pragma unroll
    for (int i = 0; i < 16; ++i) {
        int task = tid + i * 256;
        int row = task >> 6, part = task & 63;
        float4 v;
        if (part < 32) v = *(const float4*)(x + (size_t)rs[row] * 128 + part * 4);
        else           v = *(const float4*)(ea + (size_t)es[row] * 128 + (part - 32) * 4);
        short4v o;
        o[0] = (short)f2bf(v.x); o[1] = (short)f2bf(v.y);
        o[2] = (short)f2bf(v.z); o[3] = (short)f2bf(v.w);
        *(short4v*)&H0[row * 264 + part * 4] = o;
    }
    __syncthreads();

    const int lane = tid & 63;
    const int wave = tid >> 6;

    {
        floatx4 acc[4][2];
        layer_acc<256, 128, 2>(H0, 264, wt0, lane, wave * 32, acc);
        store_lds<2>(acc, b0, lane, wave * 32, H1, 136, true);
    }
    __syncthreads();
    {
        floatx4 acc[4][2];
        layer_acc<128, 128, 2>(H1, 136, wt1, lane, wave * 32, acc);
        store_lds<2>(acc, b1, lane, wave * 32, H2, 136, true);
    }
    __syncthreads();
    {
        floatx4 acc[4][2];
        layer_acc<128, 128, 2>(H2, 136, wt2, lane, wave * 32, acc);
        store_lds<2>(acc, b2, lane, wave * 32, H3, 136, true);
    }
    __syncthreads();
    {
        floatx4 acc[4][4];
        layer_acc<128, 256, 4>(H3, 136, wt3, lane, wave * 64, acc);
        __syncthreads();   // all waves done reading H3/H2 before G overwrites @0
        const int quad = lane >> 4, mrow = lane & 15;
#pragma unroll
        for (int nt = 0; nt < 4; ++nt) {
            int colg = wave * 64 + nt * 16 + mrow;
            float bv = b3[colg];
#pragma unroll
            for (int mt = 0; mt < 4; ++mt) {
#pragma unroll
                for (int r = 0; r < 4; ++r) {
                    int row = mt * 16 + quad * 4 + r;
                    float v = acc[mt][nt][r] + bv;
                    v = v > 0.f ? v : 0.f;
                    G[row * 264 + colg] = f2bf(v);
                }
            }
        }
    }
    __syncthreads();

    // Run-reduction: dests sorted -> sum consecutive equal-ds rows, one atomic per (run, col).
    {
        int col = tid;            // 256 threads = 256 cols
        float sum = 0.f;
#pragma unroll 4
        for (int i = 0; i < 64; ++i) {
            sum += bf2f(G[i * 264 + col]);
            if (i == 63 || ds[i + 1] != ds[i]) {
                atomicAdd(&s[(size_t)ds[i] * 256 + col], sum);
                sum = 0.f;
            }
        }
    }
}

// ---------------- node MLP ----------------
__global__ __launch_bounds__(256, 2) void node_kernel(
    const float* __restrict__ x,
    const float* __restrict__ g,
    const float* __restrict__ s,
    const int* __restrict__ cnt,
    const unsigned short* __restrict__ wt0, const float* __restrict__ b0,
    const unsigned short* __restrict__ wt1, const float* __restrict__ b1,
    const unsigned short* __restrict__ wt2, const float* __restrict__ b2,
    const unsigned short* __restrict__ wt3, const float* __restrict__ b3,
    float* __restrict__ out)
{
    // Aliased LDS (71680 B -> 2 blocks/CU):
    //   Abig [64][424] bf16 @0     (54272 B) - layer0 in
    //   HsA  [64][136] bf16 @54272 (17408 B) - layer0 out / layer1 in, then layer2 out / layer3 in
    //   HsB = @0 (aliases dead Abig)         - layer1 out / layer2 in
    __shared__ __align__(16) char NU[71680];
    unsigned short* Abig = (unsigned short*)NU;
    unsigned short* HsA  = (unsigned short*)(NU + 54272);
    unsigned short* HsB  = (unsigned short*)NU;

    const int tid = threadIdx.x;
    const int node0 = blockIdx.x * 64;

    // x part: cols 0..127 (fp32 -> bf16)
#pragma unroll
    for (int i = 0; i < 8; ++i) {
        int task = tid + i * 256;
        int row = task >> 5, part = task & 31;
        int node = node0 + row;
        short4v o = {0, 0, 0, 0};
        if (node < N_NODES) {
            float4 v = *(const float4*)(x + (size_t)node * 128 + part * 4);
            o[0] = (short)f2bf(v.x); o[1] = (short)f2bf(v.y);
            o[2] = (short)f2bf(v.z); o[3] = (short)f2bf(v.w);
        }
        *(short4v*)&Abig[row * 424 + part * 4] = o;
    }
    // agg part: cols 128..383 (s / max(cnt,1), fp32 -> bf16)
#pragma unroll
    for (int i = 0; i < 16; ++i) {
        int task = tid + i * 256;
        int row = task >> 6, part = task & 63;
        int node = node0 + row;
        short4v o = {0, 0, 0, 0};
        if (node < N_NODES) {
            float c = (float)cnt[node];
            float inv = 1.f / (c > 1.f ? c : 1.f);
            floatx4 v = *(const floatx4*)(s + (size_t)node * 256 + part * 4);
            o[0] = (short)f2bf(v[0] * inv);
            o[1] = (short)f2bf(v[1] * inv);
            o[2] = (short)f2bf(v[2] * inv);
            o[3] = (short)f2bf(v[3] * inv);
        }
        *(short4v*)&Abig[row * 424 + 128 + part * 4] = o;
    }
    // global part: cols 384..415
#pragma unroll
    for (int i = 0; i < 2; ++i) {
        int task = tid + i * 256;
        int row = task >> 3, part = task & 7;
        float4 v = *(const float4*)(g + part * 4);
        short4v o;
        o[0] = (short)f2bf(v.x); o[1] = (short)f2bf(v.y);
        o[2] = (short)f2bf(v.z); o[3] = (short)f2bf(v.w);
        *(short4v*)&Abig[row * 424 + 384 + part * 4] = o;
    }
    __syncthreads();

    const int lane = tid & 63;
    const int wave = tid >> 6;

    {
        floatx4 acc[4][2];
        layer_acc<416, 128, 2>(Abig, 424, wt0, lane, wave * 32, acc);
        store_lds<2>(acc, b0, lane, wave * 32, HsA, 136, true);
    }
    __syncthreads();
    {
        floatx4 acc[4][2];
        layer_acc<128, 128, 2>(HsA, 136, wt1, lane, wave * 32, acc);
        __syncthreads();   // all waves done reading Abig region before HsB overwrites @0
        store_lds<2>(acc, b1, lane, wave * 32, HsB, 136, true);
    }
    __syncthreads();
    {
        floatx4 acc[4][2];
        layer_acc<128, 128, 2>(HsB, 136, wt2, lane, wave * 32, acc);
        store_lds<2>(acc, b2, lane, wave * 32, HsA, 136, true);
    }
    __syncthreads();
    {
        floatx4 acc[4][2];
        layer_acc<128, 128, 2>(HsA, 136, wt3, lane, wave * 32, acc);
        const int quad = lane >> 4, mrow = lane & 15;
#pragma unroll
        for (int nt = 0; nt < 2; ++nt) {
            int col = wave * 32 + nt * 16 + mrow;
            float bv = b3[col];
#pragma unroll
            for (int mt = 0; mt < 4; ++mt) {
#pragma unroll
                for (int r = 0; r < 4; ++r) {
                    int row = mt * 16 + quad * 4 + r;
                    int node = node0 + row;
                    if (node < N_NODES)
                        out[(size_t)node * 128 + col] = acc[mt][nt][r] + bv;  // fp32 output
                }
            }
        }
    }
}

extern "C" void kernel_launch(void* const* d_in, const int* in_sizes, int n_in,
                              void* d_out, int out_size, void* d_ws, size_t ws_size,
                              hipStream_t stream)
{
    (void)in_sizes; (void)n_in; (void)out_size; (void)ws_size;

    const float* x  = (const float*)d_in[0];
    const int* eidx = (const int*)d_in[1];
    const float* ea = (const float*)d_in[2];
    const float* g  = (const float*)d_in[3];

    const float* w1[4]  = { (const float*)d_in[4],  (const float*)d_in[6],
                            (const float*)d_in[8],  (const float*)d_in[10] };
    const float* bb1[4] = { (const float*)d_in[5],  (const float*)d_in[7],
                            (const float*)d_in[9],  (const float*)d_in[11] };
    const float* w2[4]  = { (const float*)d_in[12], (const float*)d_in[14],
                            (const float*)d_in[16], (const float*)d_in[18] };
    const float* bb2[4] = { (const float*)d_in[13], (const float*)d_in[15],
                            (const float*)d_in[17], (const float*)d_in[19] };

    char* p = (char*)d_ws;
    unsigned short* wt1_0 = (unsigned short*)p; p += 256 * 128 * 2;
    unsigned short* wt1_1 = (unsigned short*)p; p += 128 * 128 * 2;
    unsigned short* wt1_2 = (unsigned short*)p; p += 128 * 128 * 2;
    unsigned short* wt1_3 = (unsigned short*)p; p += 128 * 256 * 2;
    unsigned short* wt2_0 = (unsigned short*)p; p += 416 * 128 * 2;
    unsigned short* wt2_1 = (unsigned short*)p; p += 128 * 128 * 2;
    unsigned short* wt2_2 = (unsigned short*)p; p += 128 * 128 * 2;
    unsigned short* wt2_3 = (unsigned short*)p; p += 128 * 128 * 2;
    float* s   = (float*)p; p += (size_t)N_NODES * 256 * 4;
    int* cnt   = (int*)p;   p += (size_t)N_NODES * 4;
    int* fill  = (int*)p;   p += (size_t)N_NODES * 4;
    int* elist = (int*)p;   p += (size_t)E_EDGES * 4;
    int* rowp  = (int*)p;   p += (size_t)E_EDGES * 4;
    int* dstp  = (int*)p;   p += (size_t)E_EDGES * 4;

    // zero s + cnt (contiguous); other scratch fully overwritten each launch
    hipMemsetAsync(s, 0, (size_t)N_NODES * 256 * 4 + (size_t)N_NODES * 4, stream);

    TArgs ta;
    int bs = 0;
    auto set = [&](int i, const float* src, unsigned short* dst, int K, int Nn, int logN) {
        ta.d[i].src = src; ta.d[i].dst = dst; ta.d[i].nElem = K * Nn;
        ta.d[i].logN = logN; ta.d[i].blockStart = bs;
        bs += (K * Nn + 255) / 256;
    };
    set(0, w1[0], wt1_0, 256, 128, 7);
    set(1, w1[1], wt1_1, 128, 128, 7);
    set(2, w1[2], wt1_2, 128, 128, 7);
    set(3, w1[3], wt1_3, 128, 256, 8);
    set(4, w2[0], wt2_0, 416, 128, 7);
    set(5, w2[1], wt2_1, 128, 128, 7);
    set(6, w2[2], wt2_2, 128, 128, 7);
    set(7, w2[3], wt2_3, 128, 128, 7);

    hipLaunchKernelGGL(transpose_kernel, dim3(bs), dim3(256), 0, stream, ta);
    hipLaunchKernelGGL(hist_kernel, dim3(E_EDGES / 256), dim3(256), 0, stream, eidx, cnt);
    hipLaunchKernelGGL(scan_kernel, dim3(1), dim3(256), 0, stream, cnt, fill);
    hipLaunchKernelGGL(fill_kernel, dim3(E_EDGES / 256), dim3(256), 0, stream,
                       eidx, fill, elist, rowp, dstp);

    hipLaunchKernelGGL(edge_kernel, dim3(E_EDGES / 64), dim3(256), 0, stream,
                       x, ea, elist, rowp, dstp,
                       wt1_0, bb1[0], wt1_1, bb1[1], wt1_2, bb1[2], wt1_3, bb1[3],
                       s);

    hipLaunchKernelGGL(node_kernel, dim3((N_NODES + 63) / 64), dim3(256), 0, stream,
                       x, g, s, cnt,
                       wt2_0, bb2[0], wt2_1, bb2[1], wt2_2, bb2[2], wt2_3, bb2[3],
                       (float*)d_out);
}

// Round 7
// 475.590 us; speedup vs baseline: 1.3468x; 1.0403x over previous
//
#include <hip/hip_runtime.h>
#include <hip/hip_bf16.h>

#define E_EDGES 320000
#define N_NODES 10000

typedef __attribute__((ext_vector_type(8))) short short8;
typedef __attribute__((ext_vector_type(4))) float floatx4;

__device__ __forceinline__ float bf2f(unsigned short u) {
    union { unsigned int i; float f; } v; v.i = ((unsigned int)u) << 16; return v.f;
}
// pack two fp32 -> bf16x2 (RNE), low = a
__device__ __forceinline__ unsigned int pk2(float a, float b) {
    float2 t; t.x = a; t.y = b;
    __hip_bfloat162 h = __float22bfloat162_rn(t);
    union { __hip_bfloat162 h; unsigned int u; } c; c.h = h; return c.u;
}

// ---- MFMA layer, SWAPPED operands: A = weights (fragment-tiled global), B = acts (LDS).
// acc[ft][et]: D col=lane&15 -> edge (et*16+mrow), row=quad*4+r -> feature (n0+ft*16+quad*4+r).
// Weight tile layout identical to round 6 repack (operand layouts are A/B symmetric).
template<int K, int Nn, int FT, int ET>
__device__ __forceinline__ void layer_acc(const unsigned short* __restrict__ in, int istride,
                                          const unsigned short* __restrict__ wt,
                                          int lane, int n0, floatx4 (&acc)[FT][ET])
{
    const int quad = lane >> 4;
    const int mrow = lane & 15;
    floatx4 zero = {0.f, 0.f, 0.f, 0.f};
#pragma unroll
    for (int ft = 0; ft < FT; ++ft)
#pragma unroll
        for (int et = 0; et < ET; ++et)
            acc[ft][et] = zero;

#pragma unroll
    for (int kt = 0; kt < K / 32; ++kt) {
        const int koff = kt * 32 + quad * 8;
        short8 a[FT];
        short8 b[ET];
#pragma unroll
        for (int ft = 0; ft < FT; ++ft)
            a[ft] = *(const short8*)&wt[(size_t)(kt * (Nn >> 4) + (n0 >> 4) + ft) * 512 + lane * 8];
#pragma unroll
        for (int et = 0; et < ET; ++et)
            b[et] = *(const short8*)&in[(et * 16 + mrow) * istride + koff];
#pragma unroll
        for (int ft = 0; ft < FT; ++ft)
#pragma unroll
            for (int et = 0; et < ET; ++et)
                acc[ft][et] = __builtin_amdgcn_mfma_f32_16x16x32_bf16(a[ft], b[et], acc[ft][et], 0, 0, 0);
    }
}

// store D to LDS [edge][feature] bf16: 4 consecutive features per reg-quad -> one ds_write_b64
template<int FT, int ET>
__device__ __forceinline__ void store_lds(floatx4 (&acc)[FT][ET], const float* __restrict__ bias,
                                          int lane, int n0, unsigned short* __restrict__ out, int ostride,
                                          bool relu)
{
    const int quad = lane >> 4, mrow = lane & 15;
#pragma unroll
    for (int ft = 0; ft < FT; ++ft) {
        int fbase = n0 + ft * 16 + quad * 4;
        float4 bv = *(const float4*)&bias[fbase];
#pragma unroll
        for (int et = 0; et < ET; ++et) {
            int edge = et * 16 + mrow;
            float v0 = acc[ft][et][0] + bv.x;
            float v1 = acc[ft][et][1] + bv.y;
            float v2 = acc[ft][et][2] + bv.z;
            float v3 = acc[ft][et][3] + bv.w;
            if (relu) {
                v0 = v0 > 0.f ? v0 : 0.f; v1 = v1 > 0.f ? v1 : 0.f;
                v2 = v2 > 0.f ? v2 : 0.f; v3 = v3 > 0.f ? v3 : 0.f;
            }
            uint2 pk; pk.x = pk2(v0, v1); pk.y = pk2(v2, v3);
            *(uint2*)&out[edge * ostride + fbase] = pk;
        }
    }
}

// ---------------- fused prep: weight repack + degree histogram ----------------
struct TDesc { const float* src; unsigned short* dst; int nElem; int logN; int blockStart; };
struct TArgs { TDesc d[8]; };

__global__ void prep_kernel(TArgs a, const int* __restrict__ eidx, int* __restrict__ cnt, int histStart)
{
    int b = blockIdx.x;
    if (b >= histStart) {
        int e = (b - histStart) * 256 + threadIdx.x;
        if (e < E_EDGES) atomicAdd(&cnt[eidx[E_EDGES + e]], 1);
        return;
    }
    int i = 0;
#pragma unroll
    for (int j = 1; j < 8; ++j)
        if (b >= a.d[j].blockStart) i = j;
    const TDesc t = a.d[i];
    int idx = (b - t.blockStart) * 256 + threadIdx.x;
    if (idx < t.nElem) {
        int n = idx & ((1 << t.logN) - 1);
        int k = idx >> t.logN;
        int ntiles = 1 << (t.logN - 4);
        size_t dsti = ((size_t)(k >> 5) * ntiles + (n >> 4)) * 512
                    + ((k >> 3) & 3) * 128 + (n & 15) * 8 + (k & 7);
        union { float f; unsigned int u; } c; c.f = t.src[idx];
        unsigned int uu = c.u;
        t.dst[dsti] = (unsigned short)((uu + 0x7fffu + ((uu >> 16) & 1u)) >> 16);
    }
}

__global__ void scan_kernel(const int* __restrict__ cnt, int* __restrict__ fill)
{
    __shared__ int partial[256];
    const int CH = 40;                      // 256*40 = 10240 >= N_NODES
    int tid = threadIdx.x;
    int base = tid * CH;
    int local[CH];
    int sum = 0;
#pragma unroll
    for (int j = 0; j < CH; ++j) {
        int idx = base + j;
        int c = (idx < N_NODES) ? cnt[idx] : 0;
        local[j] = c;
        sum += c;
    }
    partial[tid] = sum;
    __syncthreads();
    for (int o = 1; o < 256; o <<= 1) {
        int v = (tid >= o) ? partial[tid - o] : 0;
        __syncthreads();
        partial[tid] += v;
        __syncthreads();
    }
    int run = partial[tid] - sum;
#pragma unroll
    for (int j = 0; j < CH; ++j) {
        int idx = base + j;
        if (idx < N_NODES) fill[idx] = run;
        run += local[j];
    }
}

__global__ void fill_kernel(const int* __restrict__ eidx, int* __restrict__ fill,
                            int* __restrict__ elist, int* __restrict__ rowp, int* __restrict__ dstp)
{
    int e = blockIdx.x * 256 + threadIdx.x;
    int c = eidx[E_EDGES + e];
    int r = eidx[e];
    int pos = atomicAdd(&fill[c], 1);
    elist[pos] = e;
    rowp[pos] = r;
    dstp[pos] = c;
}

// ---------------- edge MLP over destination-sorted edges + run-reduced scatter ----------------
__global__ __launch_bounds__(256, 3) void edge_kernel(
    const float* __restrict__ x,
    const float* __restrict__ ea,
    const int* __restrict__ elist, const int* __restrict__ rowp, const int* __restrict__ dstp,
    const unsigned short* __restrict__ wt0, const float* __restrict__ b0,
    const unsigned short* __restrict__ wt1, const float* __restrict__ b1,
    const unsigned short* __restrict__ wt2, const float* __restrict__ b2,
    const unsigned short* __restrict__ wt3, const float* __restrict__ b3,
    float* __restrict__ s)
{
    // Aliased LDS (51200 B -> 3 blocks/CU):
    //   H0 [64][264] @0; H1 [64][136] @33792; H2=@0 (H0 dead); H3=@33792 (H1 dead);
    //   G [64][264] bf16 @0 (H2 dead after pre-L3 barrier -> safe to write during L3).
    __shared__ __align__(16) char U[51200];
    __shared__ int es[64];
    __shared__ int rs[64];
    __shared__ int ds[64];

    unsigned short* H0 = (unsigned short*)U;
    unsigned short* H1 = (unsigned short*)(U + 33792);
    unsigned short* H2 = (unsigned short*)U;
    unsigned short* H3 = H1;
    unsigned short* G  = (unsigned short*)U;

    const int tid = threadIdx.x;
    const int p0 = blockIdx.x * 64;

    if (tid < 64) {
        es[tid] = elist[p0 + tid];
        rs[tid] = rowp[p0 + tid];
        ds[tid] = dstp[p0 + tid];
    }
    __syncthreads();

    // Stage H0 = [x[src] | edge_attr[e]] : 64 rows x 256 cols, fp32 -> bf16x2 packed
#pragma unroll
    for (int i = 0; i < 16; ++i) {
        int task = tid + i * 256;
        int row = task >> 6, part = task & 63;
        float4 v;
        if (part < 32) v = *(const float4*)(x + (size_t)rs[row] * 128 + part * 4);
        else           v = *(const float4*)(ea + (size_t)es[row] * 128 + (part - 32) * 4);
        uint2 pk; pk.x = pk2(v.x, v.y); pk.y = pk2(v.z, v.w);
        *(uint2*)&H0[row * 264 + part * 4] = pk;
    }
    __syncthreads();

    const int lane = tid & 63;
    const int wave = tid >> 6;

    {
        floatx4 acc[2][4];
        layer_acc<256, 128, 2, 4>(H0, 264, wt0, lane, wave * 32, acc);
        store_lds<2, 4>(acc, b0, lane, wave * 32, H1, 136, true);
    }
    __syncthreads();
    {
        floatx4 acc[2][4];
        layer_acc<128, 128, 2, 4>(H1, 136, wt1, lane, wave * 32, acc);
        store_lds<2, 4>(acc, b1, lane, wave * 32, H2, 136, true);
    }
    __syncthreads();
    {
        floatx4 acc[2][4];
        layer_acc<128, 128, 2, 4>(H2, 136, wt2, lane, wave * 32, acc);
        store_lds<2, 4>(acc, b2, lane, wave * 32, H3, 136, true);
    }
    __syncthreads();
    {
        floatx4 acc[4][4];
        layer_acc<128, 256, 4, 4>(H3, 136, wt3, lane, wave * 64, acc);
        // G (@0) overwrites H2 region: safe — all H2 reads finished at the pre-L3 barrier.
        store_lds<4, 4>(acc, b3, lane, wave * 64, G, 264, true);
    }
    __syncthreads();

    // Run-reduction over sorted dests: 256 threads = 128 col-pairs x 2 row-halves.
    {
        int p = tid & 127;
        int half = tid >> 7;
        int col2 = p * 2;
        int base = half * 32;
        float s0 = 0.f, s1 = 0.f;
#pragma unroll 4
        for (int i = 0; i < 32; ++i) {
            int gi = base + i;
            unsigned int u = *(const unsigned int*)&G[gi * 264 + col2];
            s0 += bf2f((unsigned short)u);
            s1 += bf2f((unsigned short)(u >> 16));
            if (i == 31 || ds[gi + 1] != ds[gi]) {
                float* dst = &s[(size_t)ds[gi] * 256 + col2];
                atomicAdd(dst, s0);
                atomicAdd(dst + 1, s1);
                s0 = 0.f; s1 = 0.f;
            }
        }
    }
}

// ---------------- node MLP ----------------
__global__ __launch_bounds__(256, 2) void node_kernel(
    const float* __restrict__ x,
    const float* __restrict__ g,
    const float* __restrict__ s,
    const int* __restrict__ cnt,
    const unsigned short* __restrict__ wt0, const float* __restrict__ b0,
    const unsigned short* __restrict__ wt1, const float* __restrict__ b1,
    const unsigned short* __restrict__ wt2, const float* __restrict__ b2,
    const unsigned short* __restrict__ wt3, const float* __restrict__ b3,
    float* __restrict__ out)
{
    // Aliased LDS (71680 B -> 2 blocks/CU):
    //   Abig [64][424] @0; HsA [64][136] @54272; HsB=@0 (Abig dead after pre-L1 barrier).
    __shared__ __align__(16) char NU[71680];
    unsigned short* Abig = (unsigned short*)NU;
    unsigned short* HsA  = (unsigned short*)(NU + 54272);
    unsigned short* HsB  = (unsigned short*)NU;

    const int tid = threadIdx.x;
    const int node0 = blockIdx.x * 64;

    // x part: cols 0..127
#pragma unroll
    for (int i = 0; i < 8; ++i) {
        int task = tid + i * 256;
        int row = task >> 5, part = task & 31;
        int node = node0 + row;
        uint2 pk = {0u, 0u};
        if (node < N_NODES) {
            float4 v = *(const float4*)(x + (size_t)node * 128 + part * 4);
            pk.x = pk2(v.x, v.y); pk.y = pk2(v.z, v.w);
        }
        *(uint2*)&Abig[row * 424 + part * 4] = pk;
    }
    // agg part: cols 128..383 (s / max(cnt,1))
#pragma unroll
    for (int i = 0; i < 16; ++i) {
        int task = tid + i * 256;
        int row = task >> 6, part = task & 63;
        int node = node0 + row;
        uint2 pk = {0u, 0u};
        if (node < N_NODES) {
            float c = (float)cnt[node];
            float inv = 1.f / (c > 1.f ? c : 1.f);
            floatx4 v = *(const floatx4*)(s + (size_t)node * 256 + part * 4);
            pk.x = pk2(v[0] * inv, v[1] * inv);
            pk.y = pk2(v[2] * inv, v[3] * inv);
        }
        *(uint2*)&Abig[row * 424 + 128 + part * 4] = pk;
    }
    // global part: cols 384..415
#pragma unroll
    for (int i = 0; i < 2; ++i) {
        int task = tid + i * 256;
        int row = task >> 3, part = task & 7;
        float4 v = *(const float4*)(g + part * 4);
        uint2 pk; pk.x = pk2(v.x, v.y); pk.y = pk2(v.z, v.w);
        *(uint2*)&Abig[row * 424 + 384 + part * 4] = pk;
    }
    __syncthreads();

    const int lane = tid & 63;
    const int wave = tid >> 6;

    {
        floatx4 acc[2][4];
        layer_acc<416, 128, 2, 4>(Abig, 424, wt0, lane, wave * 32, acc);
        store_lds<2, 4>(acc, b0, lane, wave * 32, HsA, 136, true);
    }
    __syncthreads();
    {
        floatx4 acc[2][4];
        // HsB (@0) overwrites Abig: safe — all Abig reads finished at the pre-L1 barrier.
        layer_acc<128, 128, 2, 4>(HsA, 136, wt1, lane, wave * 32, acc);
        store_lds<2, 4>(acc, b1, lane, wave * 32, HsB, 136, true);
    }
    __syncthreads();
    {
        floatx4 acc[2][4];
        layer_acc<128, 128, 2, 4>(HsB, 136, wt2, lane, wave * 32, acc);
        store_lds<2, 4>(acc, b2, lane, wave * 32, HsA, 136, true);
    }
    __syncthreads();
    {
        floatx4 acc[2][4];
        layer_acc<128, 128, 2, 4>(HsA, 136, wt3, lane, wave * 32, acc);
        const int quad = lane >> 4, mrow = lane & 15;
#pragma unroll
        for (int ft = 0; ft < 2; ++ft) {
            int fbase = wave * 32 + ft * 16 + quad * 4;
            float4 bv = *(const float4*)&b3[fbase];
#pragma unroll
            for (int et = 0; et < 4; ++et) {
                int node = node0 + et * 16 + mrow;
                if (node < N_NODES) {
                    float4 o;
                    o.x = acc[ft][et][0] + bv.x;
                    o.y = acc[ft][et][1] + bv.y;
                    o.z = acc[ft][et][2] + bv.z;
                    o.w = acc[ft][et][3] + bv.w;
                    *(float4*)&out[(size_t)node * 128 + fbase] = o;  // fp32 vectorized
                }
            }
        }
    }
}

extern "C" void kernel_launch(void* const* d_in, const int* in_sizes, int n_in,
                              void* d_out, int out_size, void* d_ws, size_t ws_size,
                              hipStream_t stream)
{
    (void)in_sizes; (void)n_in; (void)out_size; (void)ws_size;

    const float* x  = (const float*)d_in[0];
    const int* eidx = (const int*)d_in[1];
    const float* ea = (const float*)d_in[2];
    const float* g  = (const float*)d_in[3];

    const float* w1[4]  = { (const float*)d_in[4],  (const float*)d_in[6],
                            (const float*)d_in[8],  (const float*)d_in[10] };
    const float* bb1[4] = { (const float*)d_in[5],  (const float*)d_in[7],
                            (const float*)d_in[9],  (const float*)d_in[11] };
    const float* w2[4]  = { (const float*)d_in[12], (const float*)d_in[14],
                            (const float*)d_in[16], (const float*)d_in[18] };
    const float* bb2[4] = { (const float*)d_in[13], (const float*)d_in[15],
                            (const float*)d_in[17], (const float*)d_in[19] };

    char* p = (char*)d_ws;
    unsigned short* wt1_0 = (unsigned short*)p; p += 256 * 128 * 2;
    unsigned short* wt1_1 = (unsigned short*)p; p += 128 * 128 * 2;
    unsigned short* wt1_2 = (unsigned short*)p; p += 128 * 128 * 2;
    unsigned short* wt1_3 = (unsigned short*)p; p += 128 * 256 * 2;
    unsigned short* wt2_0 = (unsigned short*)p; p += 416 * 128 * 2;
    unsigned short* wt2_1 = (unsigned short*)p; p += 128 * 128 * 2;
    unsigned short* wt2_2 = (unsigned short*)p; p += 128 * 128 * 2;
    unsigned short* wt2_3 = (unsigned short*)p; p += 128 * 128 * 2;
    float* s   = (float*)p; p += (size_t)N_NODES * 256 * 4;
    int* cnt   = (int*)p;   p += (size_t)N_NODES * 4;
    int* fill  = (int*)p;   p += (size_t)N_NODES * 4;
    int* elist = (int*)p;   p += (size_t)E_EDGES * 4;
    int* rowp  = (int*)p;   p += (size_t)E_EDGES * 4;
    int* dstp  = (int*)p;   p += (size_t)E_EDGES * 4;

    // zero s + cnt (contiguous); other scratch fully overwritten each launch
    hipMemsetAsync(s, 0, (size_t)N_NODES * 256 * 4 + (size_t)N_NODES * 4, stream);

    TArgs ta;
    int bs = 0;
    auto set = [&](int i, const float* src, unsigned short* dst, int K, int Nn, int logN) {
        ta.d[i].src = src; ta.d[i].dst = dst; ta.d[i].nElem = K * Nn;
        ta.d[i].logN = logN; ta.d[i].blockStart = bs;
        bs += (K * Nn + 255) / 256;
    };
    set(0, w1[0], wt1_0, 256, 128, 7);
    set(1, w1[1], wt1_1, 128, 128, 7);
    set(2, w1[2], wt1_2, 128, 128, 7);
    set(3, w1[3], wt1_3, 128, 256, 8);
    set(4, w2[0], wt2_0, 416, 128, 7);
    set(5, w2[1], wt2_1, 128, 128, 7);
    set(6, w2[2], wt2_2, 128, 128, 7);
    set(7, w2[3], wt2_3, 128, 128, 7);

    int histBlocks = E_EDGES / 256;
    hipLaunchKernelGGL(prep_kernel, dim3(bs + histBlocks), dim3(256), 0, stream,
                       ta, eidx, cnt, bs);
    hipLaunchKernelGGL(scan_kernel, dim3(1), dim3(256), 0, stream, cnt, fill);
    hipLaunchKernelGGL(fill_kernel, dim3(E_EDGES / 256), dim3(256), 0, stream,
                       eidx, fill, elist, rowp, dstp);

    hipLaunchKernelGGL(edge_kernel, dim3(E_EDGES / 64), dim3(256), 0, stream,
                       x, ea, elist, rowp, dstp,
                       wt1_0, bb1[0], wt1_1, bb1[1], wt1_2, bb1[2], wt1_3, bb1[3],
                       s);

    hipLaunchKernelGGL(node_kernel, dim3((N_NODES + 63) / 64), dim3(256), 0, stream,
                       x, g, s, cnt,
                       wt2_0, bb2[0], wt2_1, bb2[1], wt2_2, bb2[2], wt2_3, bb2[3],
                       (float*)d_out);
}